// Round 3
// baseline (53728.717 us; speedup 1.0000x reference)
//
#include <hip/hip_runtime.h>
#include <math.h>
#include <float.h>

// Problem constants: B=256, H=1024, I=1, O=512, T=512
#define NT 512

// Workspace layout (float offsets)
// hT4 layout: [q=u>>2][b][j=u&3] -> q*1024 + b*4 + j  (256K floats = 1 MB)
#define OFF_HT4_0 0
#define OFF_HT4_1 (256*1024)
#define OFF_PART  (2*256*1024)              // partials [og=16][b=256][{val,idx}]
#define OFF_BAR   (OFF_PART + 16*256*2)     // int barrier counter

__device__ __forceinline__ float sigf(float x) { return 1.f / (1.f + expf(-x)); }

#define FMA4(A, W, H) \
  A = fmaf((W).x, (H).x, A); A = fmaf((W).y, (H).y, A); \
  A = fmaf((W).z, (H).z, A); A = fmaf((W).w, (H).w, A);

// ---------------------------------------------------------------------------
// Init: pack h0=z into hT4 ping, seed argmax partials to (-FLT_MAX, 0) so the
// t=0 gates phase sees xin=0, zero the grid-barrier counter.
// ---------------------------------------------------------------------------
__global__ void k_init(const float* __restrict__ z, float* __restrict__ ws) {
  int idx = blockIdx.x * 256 + threadIdx.x;
  if (idx < 256 * 1024) {                   // hT4[q][b][j] = z[b][q*4+j]
    int q = idx >> 10, r = idx & 1023;
    int b = r >> 2, j = r & 3;
    ws[OFF_HT4_0 + idx] = z[b * 1024 + (q << 2) + j];
  }
  if (idx < 16 * 256 * 2) ws[OFF_PART + idx] = (idx & 1) ? 0.f : -FLT_MAX;
  if (idx == 0) *(int*)(ws + OFF_BAR) = 0;
}

// Device-scope grid barrier (sense-free monotonic counter). All 256 blocks are
// co-resident (grid == #CUs, 1 block/CU by LDS/occupancy), so spinning is safe.
__device__ __forceinline__ void gridbar(int* bar, int target) {
  __syncthreads();
  if (threadIdx.x == 0) {
    __threadfence();                         // agent release: drain + L2 wb
    __hip_atomic_fetch_add(bar, 1, __ATOMIC_ACQ_REL, __HIP_MEMORY_SCOPE_AGENT);
    while (__hip_atomic_load(bar, __ATOMIC_ACQUIRE, __HIP_MEMORY_SCOPE_AGENT) < target)
      __builtin_amdgcn_s_sleep(4);
  }
  __syncthreads();
}

// ---------------------------------------------------------------------------
// Persistent kernel: 256 blocks x 256 threads, whole T-loop in one launch.
// Per step: [xin-reduce prologue + gates matmul + cell update] BAR
//           [head matmul + out write + per-(og,b) argmax partial] BAR.
// Block owns units u0..u0+3 (w_hh slice 64 KB in LDS, staged ONCE; c in regs
// across all 512 steps). Head: block = (bg=16 b's) x (og=32 o's).
// ---------------------------------------------------------------------------
__global__ __launch_bounds__(256, 1) void k_persist(
    const float* __restrict__ w_hh, const float* __restrict__ w_ih,
    const float* __restrict__ b_ih, const float* __restrict__ b_hh,
    const float* __restrict__ w_lin, const float* __restrict__ b_lin,
    float* out, float* ws) {
  __shared__ __align__(16) float wlds[16 * 1024];   // 64 KB, persistent
  __shared__ __align__(16) float shh[16][1028];     // head h slice (+pad)
  __shared__ float xin_s[256];

  float* ht0 = ws + OFF_HT4_0;
  float* ht1 = ws + OFF_HT4_1;
  float* part = ws + OFF_PART;
  int* bar = (int*)(ws + OFF_BAR);

  const int tid = threadIdx.x;
  const int blk = blockIdx.x;
  const int lane = tid & 63;
  const int uu = tid >> 6;
  const int u0 = blk << 2;

  // ---- one-time staging: w_hh rows (16 x 4KB), fully coalesced ----
#pragma unroll
  for (int r = 0; r < 16; ++r) {
    int ru = r >> 2, g = r & 3;             // global row g*1024 + u0 + ru
    *(float4*)(&wlds[(r << 10) + (tid << 2)]) =
        *(const float4*)(w_hh + ((g * 1024 + u0 + ru) << 10) + (tid << 2));
  }
  // one-time per-thread constants
  const int u = u0 + uu;
  const float bi = b_ih[u] + b_hh[u];
  const float bf = b_ih[1024 + u] + b_hh[1024 + u];
  const float bgc = b_ih[2048 + u] + b_hh[2048 + u];
  const float bo = b_ih[3072 + u] + b_hh[3072 + u];
  const float wi = w_ih[u], wf = w_ih[1024 + u];
  const float wg = w_ih[2048 + u], wo = w_ih[3072 + u];
  // head constants: block = (bg, og); thread = (bt, oo) -> 1 o, 2 b's
  const int og = blk & 15, bg2 = blk >> 4;
  const int oo = tid & 31, bt = tid >> 5;
  const int o = (og << 5) + oo;
  const float blr = b_lin[o];
  const float* __restrict__ wrowg = w_lin + (o << 10);

  float c[4] = {0.f, 0.f, 0.f, 0.f};        // cell state, resident all T steps
  const float* wrow = &wlds[(uu << 2) << 10];
  __syncthreads();

  int target = 0;
  for (int t = 0; t < NT; ++t) {
    float* hin  = (t & 1) ? ht1 : ht0;
    float* hout = (t & 1) ? ht0 : ht1;

    // ---- xin reduce: b = tid; ascending og + strict > = first-index wins ----
    {
      float2 p0 = *(const float2*)(part + (tid << 1));
      float v = p0.x, ix = p0.y;
#pragma unroll
      for (int g2 = 1; g2 < 16; ++g2) {
        float2 p = *(const float2*)(part + (g2 << 9) + (tid << 1));
        if (p.x > v) { v = p.x; ix = p.y; }
      }
      xin_s[tid] = ix;
    }
    __syncthreads();

    // ---- gates matmul: acc[gate][bb], both w and h double-buffered ----
    float acc[4][4];
#pragma unroll
    for (int g = 0; g < 4; ++g)
#pragma unroll
      for (int bb = 0; bb < 4; ++bb) acc[g][bb] = 0.f;

    const float* hp = hin + (lane << 2);
    float4 hA[4], hB[4], wA[4], wB[4];
#pragma unroll
    for (int bb = 0; bb < 4; ++bb) hA[bb] = *(const float4*)(hp + (bb << 8));
#pragma unroll
    for (int g = 0; g < 4; ++g) wA[g] = *(const float4*)(wrow + (g << 10));

    for (int q = 0; q < 256; q += 2) {
#pragma unroll
      for (int bb = 0; bb < 4; ++bb)
        hB[bb] = *(const float4*)(hp + ((q + 1) << 10) + (bb << 8));
#pragma unroll
      for (int g = 0; g < 4; ++g)
        wB[g] = *(const float4*)(wrow + (g << 10) + ((q + 1) << 2));
#pragma unroll
      for (int bb = 0; bb < 4; ++bb) {
        const float4 h = hA[bb];
        FMA4(acc[0][bb], wA[0], h); FMA4(acc[1][bb], wA[1], h);
        FMA4(acc[2][bb], wA[2], h); FMA4(acc[3][bb], wA[3], h);
      }
      if (q + 2 < 256) {
#pragma unroll
        for (int bb = 0; bb < 4; ++bb)
          hA[bb] = *(const float4*)(hp + ((q + 2) << 10) + (bb << 8));
#pragma unroll
        for (int g = 0; g < 4; ++g)
          wA[g] = *(const float4*)(wrow + (g << 10) + ((q + 2) << 2));
      }
#pragma unroll
      for (int bb = 0; bb < 4; ++bb) {
        const float4 h = hB[bb];
        FMA4(acc[0][bb], wB[0], h); FMA4(acc[1][bb], wB[1], h);
        FMA4(acc[2][bb], wB[2], h); FMA4(acc[3][bb], wB[3], h);
      }
    }

    // ---- cell update epilogue (c in registers) ----
#pragma unroll
    for (int bb = 0; bb < 4; ++bb) {
      const int b = lane + (bb << 6);
      const float xb = xin_s[b];
      const float gi = acc[0][bb] + bi + xb * wi;
      const float gf = acc[1][bb] + bf + xb * wf;
      const float gg = acc[2][bb] + bgc + xb * wg;
      const float go = acc[3][bb] + bo + xb * wo;
      // accurate expf/tanhf: argmax feedback needs ~1e-6 accuracy
      const float cn = sigf(gf) * c[bb] + sigf(gi) * tanhf(gg);
      c[bb] = cn;
      const float hn = sigf(go) * tanhf(cn);
      hout[(blk << 10) + (b << 2) + uu] = hn;
    }
    target += 256;
    gridbar(bar, target);

    // ---- head: stage 16-b h slice to LDS (coalesced 256B segments) ----
#pragma unroll
    for (int i = 0; i < 16; ++i) {
      int f = i * 256 + tid;                // [0, 4096) float4s
      int q = f >> 4, m4 = f & 15;          // m4 = local b
      float4 v = *(const float4*)(hout + (q << 10) + (((bg2 << 4) + m4) << 2));
      *(float4*)(&shh[m4][q << 2]) = v;
    }
    __syncthreads();

    // head matmul: 1 o x 2 b per thread; w_lin row prefetched from global(L2)
    const int b0r = bt << 1, b1r = b0r + 1; // local b rows in shh
    float a0 = 0.f, a1 = 0.f;
    float4 wv = *(const float4*)(wrowg);
#pragma unroll 4
    for (int u4 = 0; u4 < 256; ++u4) {
      const float4 w = wv;
      if (u4 + 1 < 256) wv = *(const float4*)(wrowg + ((u4 + 1) << 2));
      const float4 h0 = *(const float4*)(&shh[b0r][u4 << 2]);
      const float4 h1 = *(const float4*)(&shh[b1r][u4 << 2]);
      FMA4(a0, w, h0); FMA4(a1, w, h1);
    }
    a0 += blr; a1 += blr;

    const int bglob0 = (bg2 << 4) + b0r;
    out[(size_t)bglob0 * (NT * 512) + t * 512 + o] = a0;
    out[(size_t)(bglob0 + 1) * (NT * 512) + t * 512 + o] = a1;

    // per-(og, b) argmax over the 32 oo lanes (xor shuffle, width 32);
    // tiebreak: equal value -> lower o wins (matches first-index semantics)
    float v0 = a0, i0 = (float)o, v1 = a1, i1 = (float)o;
#pragma unroll
    for (int m = 16; m > 0; m >>= 1) {
      float vv = __shfl_xor(v0, m, 32); float ii = __shfl_xor(i0, m, 32);
      if (vv > v0 || (vv == v0 && ii < i0)) { v0 = vv; i0 = ii; }
      vv = __shfl_xor(v1, m, 32); ii = __shfl_xor(i1, m, 32);
      if (vv > v1 || (vv == v1 && ii < i1)) { v1 = vv; i1 = ii; }
    }
    if (oo == 0) {
      *(float2*)(part + (og << 9) + (bglob0 << 1)) = make_float2(v0, i0);
      *(float2*)(part + (og << 9) + ((bglob0 + 1) << 1)) = make_float2(v1, i1);
    }
    target += 256;
    gridbar(bar, target);
  }
}

extern "C" void kernel_launch(void* const* d_in, const int* in_sizes, int n_in,
                              void* d_out, int out_size, void* d_ws, size_t ws_size,
                              hipStream_t stream) {
  const float* z     = (const float*)d_in[0];
  const float* w_ih  = (const float*)d_in[1];
  const float* w_hh  = (const float*)d_in[2];
  const float* b_ih  = (const float*)d_in[3];
  const float* b_hh  = (const float*)d_in[4];
  const float* w_lin = (const float*)d_in[5];
  const float* b_lin = (const float*)d_in[6];
  float* out = (float*)d_out;
  float* ws  = (float*)d_ws;

  k_init<<<1024, 256, 0, stream>>>(z, ws);
  k_persist<<<256, 256, 0, stream>>>(w_hh, w_ih, b_ih, b_hh, w_lin, b_lin, out, ws);
}